// Round 1
// 272.391 us; speedup vs baseline: 1.0925x; 1.0925x over previous
//
#include <hip/hip_runtime.h>

#define NS 10

typedef __attribute__((ext_vector_type(8))) short bf16x8;
typedef __attribute__((ext_vector_type(4))) float f32x4;

__device__ __forceinline__ float bf2f(unsigned short u) {
  union { unsigned int i; float f; } x;
  x.i = ((unsigned int)u) << 16;
  return x.f;
}
__device__ __forceinline__ unsigned short f2bf(float f) {
  union { float f; unsigned int i; } x; x.f = f;
  unsigned int r = x.i + 0x7FFFu + ((x.i >> 16) & 1u);
  return (unsigned short)(r >> 16);
}
__device__ __forceinline__ unsigned pk2(float a, float b) {
  return (unsigned)f2bf(a) | ((unsigned)f2bf(b) << 16);
}

// ===== gprep: weight pack (fp32 [K][N] -> bf16 [N][K]) + all input gathers ==
// wt1: [mp*2+l][256][576] (cols: Ws | Wn | Wedge); wte: [mp][64][576]
#define PACKB 2592  // (2*2*256*576 + 2*64*576) / 256
struct GJob {
  const float* table; const int* idx; unsigned short* out;
  int M, D4, ns, ostride, blk0; float inv;
};
struct GJobs { GJob j[14]; };

__global__ __launch_bounds__(256) void gprep_k(
    GJobs js, int njobs,
    const float* __restrict__ Wself, const float* __restrict__ Wneigh,
    const float* __restrict__ Wedg, const float* __restrict__ Wec,
    unsigned short* __restrict__ wt1, unsigned short* __restrict__ wte) {
  int b = blockIdx.x;
  if (b < PACKB) {
    int t = b * 256 + threadIdx.x;
    const int total1 = 2 * 2 * 256 * 576;
    if (t < total1) {
      int g = t / 147456, r = t - g * 147456;
      int n = r / 576, k = r - n * 576;
      float v;
      if (k < 256) v = Wself[(long)g * 65536 + k * 256 + n];
      else if (k < 512) v = Wneigh[(long)g * 65536 + (k - 256) * 256 + n];
      else v = Wedg[(long)g * 16384 + (k - 512) * 256 + n];
      wt1[t] = f2bf(v);
    } else {
      int t2 = t - total1;  // < 2*64*576
      int mp = t2 / 36864, r = t2 - mp * 36864;
      int n = r / 576, k = r - n * 576;
      wte[t2] = f2bf(Wec[(long)(mp * 2) * 36864 + k * 64 + n]);
    }
    return;
  }
  b -= PACKB;
  int ji = 0;
  for (int k = 1; k < njobs; ++k) if (b >= js.j[k].blk0) ji = k;
  GJob jb = js.j[ji];
  int t = (b - jb.blk0) * 256 + threadIdx.x;
  int m = t / jb.D4, d4 = t - m * jb.D4;
  long D = (long)jb.D4 * 4;
  float ax = 0.f, ay = 0.f, az = 0.f, aw = 0.f;
  if (jb.ns == NS) {
    // compile-time unroll: all 10 idx loads issue, then all 10 gathers
    int ridx[NS];
#pragma unroll
    for (int s = 0; s < NS; ++s) ridx[s] = jb.idx[(long)m * NS + s];
#pragma unroll
    for (int s = 0; s < NS; ++s) {
      float4 v = *(const float4*)(jb.table + (long)ridx[s] * D + d4 * 4);
      ax += v.x; ay += v.y; az += v.z; aw += v.w;
    }
  } else {
    long r = (long)jb.idx[m];
    float4 v = *(const float4*)(jb.table + r * D + d4 * 4);
    ax = v.x; ay = v.y; az = v.z; aw = v.w;
  }
  uint2 o; o.x = pk2(ax * jb.inv, ay * jb.inv); o.y = pk2(az * jb.inv, aw * jb.inv);
  *(uint2*)(jb.out + (long)m * jb.ostride + d4 * 4) = o;
}

// ===== GEMM1: h01 = relu(A1b @ WT1[mp][0]); BM=64 BN=128, dbuf 1-barrier ====
// Also tees rows<512 (h0 level) into A3[mp][512][576] cols 0..255.
__global__ __launch_bounds__(256) void gemm1_k(
    const unsigned short* __restrict__ A, const unsigned short* __restrict__ wt1,
    unsigned short* __restrict__ C, unsigned short* __restrict__ A3) {
  __shared__ unsigned short As[2][64 * 40];
  __shared__ unsigned short Bs[2][128 * 40];
  int tid = threadIdx.x, mp = blockIdx.z;
  int m0 = blockIdx.y * 64, n0 = blockIdx.x * 128;
  const unsigned short* Ap = A + (long)mp * 5632 * 576 + (long)m0 * 576;
  const unsigned short* Bp = wt1 + (long)mp * 2 * 147456 + (long)n0 * 576;

  int arow = tid >> 2, aq = tid & 3;   // 64 rows x 64B
  int bcol = tid >> 1, bh = tid & 1;   // 128 cols x 64B (2 x 16B each)
  const unsigned short* apt = Ap + (long)arow * 576 + aq * 8;
  const unsigned short* bpt = Bp + (long)bcol * 576 + bh * 16;

  {  // prologue: stage k-step 0 into buffer 0
    uint4 a = *(const uint4*)apt;
    uint4 b0 = *(const uint4*)bpt, b1 = *(const uint4*)(bpt + 8);
    *(uint4*)&As[0][arow * 40 + aq * 8] = a;
    *(uint4*)&Bs[0][bcol * 40 + bh * 16] = b0;
    *(uint4*)&Bs[0][bcol * 40 + bh * 16 + 8] = b1;
  }
  __syncthreads();

  f32x4 acc[2][4];
#pragma unroll
  for (int i = 0; i < 2; ++i)
#pragma unroll
    for (int j = 0; j < 4; ++j) acc[i][j] = (f32x4){0.f, 0.f, 0.f, 0.f};

  int wave = tid >> 6, lane = tid & 63;
  int wm = wave >> 1, wn = wave & 1;
  int quad = lane >> 4, r16 = lane & 15;

  for (int it = 0; it < 18; ++it) {
    uint4 na, nb0, nb1;
    bool pf = (it + 1 < 18);
    if (pf) {  // issue next tile's loads before compute
      na  = *(const uint4*)(apt + (it + 1) * 32);
      nb0 = *(const uint4*)(bpt + (it + 1) * 32);
      nb1 = *(const uint4*)(bpt + (it + 1) * 32 + 8);
    }
    int c = it & 1;
    bf16x8 af[2], bfr[4];
#pragma unroll
    for (int i = 0; i < 2; ++i)
      af[i] = *(const bf16x8*)&As[c][(wm * 32 + i * 16 + r16) * 40 + quad * 8];
#pragma unroll
    for (int j = 0; j < 4; ++j)
      bfr[j] = *(const bf16x8*)&Bs[c][(wn * 64 + j * 16 + r16) * 40 + quad * 8];
#pragma unroll
    for (int i = 0; i < 2; ++i)
#pragma unroll
      for (int j = 0; j < 4; ++j)
        acc[i][j] = __builtin_amdgcn_mfma_f32_16x16x32_bf16(af[i], bfr[j], acc[i][j], 0, 0, 0);
    if (pf) {
      *(uint4*)&As[c ^ 1][arow * 40 + aq * 8] = na;
      *(uint4*)&Bs[c ^ 1][bcol * 40 + bh * 16] = nb0;
      *(uint4*)&Bs[c ^ 1][bcol * 40 + bh * 16 + 8] = nb1;
      __syncthreads();
    }
  }
#pragma unroll
  for (int i = 0; i < 2; ++i) {
#pragma unroll
    for (int j = 0; j < 4; ++j) {
#pragma unroll
      for (int r = 0; r < 4; ++r) {
        int row = m0 + wm * 32 + i * 16 + quad * 4 + r;
        int col = n0 + wn * 64 + j * 16 + r16;
        unsigned short u = f2bf(fmaxf(acc[i][j][r], 0.f));
        C[(long)mp * 5632 * 256 + (long)row * 256 + col] = u;
        if (row < 512)
          A3[(long)mp * 512 * 576 + (long)row * 576 + col] = u;
      }
    }
  }
}

// ===== edge GEMM: enew = tanh([h0(rep10)|h1|eg0] @ WTe + be); dbuf =========
__device__ __forceinline__ const unsigned short* edgeA(
    const unsigned short* h0, const unsigned short* h1, const unsigned short* eg,
    int ar0, int gr, int q, int it) {
  if (it < 8)  return h0 + (long)ar0 * 256 + it * 32 + q * 8;
  if (it < 16) return h1 + (long)gr * 256 + (it - 8) * 32 + q * 8;
  return eg + (long)gr * 64 + (it - 16) * 32 + q * 8;
}

__global__ __launch_bounds__(256) void edge_k(
    const unsigned short* __restrict__ h01, const unsigned short* __restrict__ eg0,
    const unsigned short* __restrict__ wte, const float* __restrict__ bec,
    unsigned short* __restrict__ enew) {
  __shared__ unsigned short As[2][64 * 40];
  __shared__ unsigned short Bs[2][64 * 40];
  int tid = threadIdx.x, mp = blockIdx.z;
  int m0 = blockIdx.y * 64;
  const unsigned short* h0 = h01 + (long)mp * 5632 * 256;
  const unsigned short* h1 = h0 + 512 * 256;
  const unsigned short* eg = eg0 + (long)mp * 5120 * 64;
  const unsigned short* Bp = wte + (long)mp * 36864;

  int row = tid >> 2, q = tid & 3;
  int gr = m0 + row;
  int ar0 = gr / 10;
  const unsigned short* bpt = Bp + (long)row * 576 + q * 8;

  {  // prologue it=0
    uint4 a = *(const uint4*)edgeA(h0, h1, eg, ar0, gr, q, 0);
    uint4 bv = *(const uint4*)bpt;
    *(uint4*)&As[0][row * 40 + q * 8] = a;
    *(uint4*)&Bs[0][row * 40 + q * 8] = bv;
  }
  __syncthreads();

  f32x4 acc[2][2];
#pragma unroll
  for (int i = 0; i < 2; ++i)
#pragma unroll
    for (int j = 0; j < 2; ++j) acc[i][j] = (f32x4){0.f, 0.f, 0.f, 0.f};

  int wave = tid >> 6, lane = tid & 63;
  int wm = wave >> 1, wn = wave & 1;
  int quad = lane >> 4, r16 = lane & 15;

  for (int it = 0; it < 18; ++it) {
    uint4 na, nb;
    bool pf = (it + 1 < 18);
    if (pf) {
      na = *(const uint4*)edgeA(h0, h1, eg, ar0, gr, q, it + 1);
      nb = *(const uint4*)(bpt + (it + 1) * 32);
    }
    int c = it & 1;
    bf16x8 af[2], bfr[2];
#pragma unroll
    for (int i = 0; i < 2; ++i)
      af[i] = *(const bf16x8*)&As[c][(wm * 32 + i * 16 + r16) * 40 + quad * 8];
#pragma unroll
    for (int j = 0; j < 2; ++j)
      bfr[j] = *(const bf16x8*)&Bs[c][(wn * 32 + j * 16 + r16) * 40 + quad * 8];
#pragma unroll
    for (int i = 0; i < 2; ++i)
#pragma unroll
      for (int j = 0; j < 2; ++j)
        acc[i][j] = __builtin_amdgcn_mfma_f32_16x16x32_bf16(af[i], bfr[j], acc[i][j], 0, 0, 0);
    if (pf) {
      *(uint4*)&As[c ^ 1][row * 40 + q * 8] = na;
      *(uint4*)&Bs[c ^ 1][row * 40 + q * 8] = nb;
      __syncthreads();
    }
  }
#pragma unroll
  for (int i = 0; i < 2; ++i) {
#pragma unroll
    for (int j = 0; j < 2; ++j) {
#pragma unroll
      for (int r = 0; r < 4; ++r) {
        int rr = m0 + wm * 32 + i * 16 + quad * 4 + r;
        int cc = wn * 32 + j * 16 + r16;
        float v = tanhf(acc[i][j][r] + bec[mp * 128 + cc]);
        enew[(long)mp * 5120 * 64 + (long)rr * 64 + cc] = f2bf(v);
      }
    }
  }
}

// ===== meanprep: A3[mp][m][256..511] = mean10(h1), [512..575] = mean10(enew)
__global__ __launch_bounds__(256) void meanprep_k(
    const unsigned short* __restrict__ h01, const unsigned short* __restrict__ enew,
    unsigned short* __restrict__ A3) {
  int mp = blockIdx.y;
  int t = blockIdx.x * 256 + threadIdx.x;  // 20480 per mp
  const unsigned short* h1 = h01 + (long)mp * 5632 * 256 + 512 * 256;
  const unsigned short* en = enew + (long)mp * 5120 * 64;
  unsigned short* Am = A3 + (long)mp * 512 * 576;
  const unsigned short* src; int m, d8, K, ocol;
  if (t < 16384) { m = t >> 5; d8 = t & 31; src = h1; K = 256; ocol = 256 + d8 * 8; }
  else { int t2 = t - 16384; m = t2 >> 3; d8 = t2 & 7; src = en; K = 64; ocol = 512 + d8 * 8; }
  float s[8];
#pragma unroll
  for (int x = 0; x < 8; ++x) s[x] = 0.f;
#pragma unroll
  for (int ss = 0; ss < NS; ++ss) {
    uint4 v = *(const uint4*)(src + (long)(m * NS + ss) * K + d8 * 8);
    unsigned vals[4] = {v.x, v.y, v.z, v.w};
#pragma unroll
    for (int x = 0; x < 4; ++x) {
      s[x * 2]     += bf2f((unsigned short)(vals[x] & 0xFFFF));
      s[x * 2 + 1] += bf2f((unsigned short)(vals[x] >> 16));
    }
  }
  uint4 o;
  o.x = pk2(s[0] * 0.1f, s[1] * 0.1f);
  o.y = pk2(s[2] * 0.1f, s[3] * 0.1f);
  o.z = pk2(s[4] * 0.1f, s[5] * 0.1f);
  o.w = pk2(s[6] * 0.1f, s[7] * 0.1f);
  *(uint4*)(Am + (long)m * 576 + ocol) = o;
}

// ===== GEMM3: osum = A3 @ WT1[mp][1]; BM=64 BN=64, dbuf, fp32 out ==========
__global__ __launch_bounds__(256) void gemm3_k(
    const unsigned short* __restrict__ A3, const unsigned short* __restrict__ wt1,
    float* __restrict__ osum) {
  __shared__ unsigned short As[2][64 * 40];
  __shared__ unsigned short Bs[2][64 * 40];
  int tid = threadIdx.x, mp = blockIdx.z;
  int n0 = blockIdx.x * 64, m0 = blockIdx.y * 64;
  const unsigned short* Ap = A3 + (long)mp * 512 * 576 + (long)m0 * 576;
  const unsigned short* Bp = wt1 + (long)(mp * 2 + 1) * 147456 + (long)n0 * 576;

  int row = tid >> 2, q = tid & 3;
  const unsigned short* apt = Ap + (long)row * 576 + q * 8;
  const unsigned short* bpt = Bp + (long)row * 576 + q * 8;

  {
    uint4 a = *(const uint4*)apt;
    uint4 bv = *(const uint4*)bpt;
    *(uint4*)&As[0][row * 40 + q * 8] = a;
    *(uint4*)&Bs[0][row * 40 + q * 8] = bv;
  }
  __syncthreads();

  f32x4 acc[2][2];
#pragma unroll
  for (int i = 0; i < 2; ++i)
#pragma unroll
    for (int j = 0; j < 2; ++j) acc[i][j] = (f32x4){0.f, 0.f, 0.f, 0.f};

  int wave = tid >> 6, lane = tid & 63;
  int wm = wave >> 1, wn = wave & 1;
  int quad = lane >> 4, r16 = lane & 15;

  for (int it = 0; it < 18; ++it) {
    uint4 na, nb;
    bool pf = (it + 1 < 18);
    if (pf) {
      na = *(const uint4*)(apt + (it + 1) * 32);
      nb = *(const uint4*)(bpt + (it + 1) * 32);
    }
    int c = it & 1;
    bf16x8 af[2], bfr[2];
#pragma unroll
    for (int i = 0; i < 2; ++i)
      af[i] = *(const bf16x8*)&As[c][(wm * 32 + i * 16 + r16) * 40 + quad * 8];
#pragma unroll
    for (int j = 0; j < 2; ++j)
      bfr[j] = *(const bf16x8*)&Bs[c][(wn * 32 + j * 16 + r16) * 40 + quad * 8];
#pragma unroll
    for (int i = 0; i < 2; ++i)
#pragma unroll
      for (int j = 0; j < 2; ++j)
        acc[i][j] = __builtin_amdgcn_mfma_f32_16x16x32_bf16(af[i], bfr[j], acc[i][j], 0, 0, 0);
    if (pf) {
      *(uint4*)&As[c ^ 1][row * 40 + q * 8] = na;
      *(uint4*)&Bs[c ^ 1][row * 40 + q * 8] = nb;
      __syncthreads();
    }
  }
#pragma unroll
  for (int i = 0; i < 2; ++i) {
#pragma unroll
    for (int j = 0; j < 2; ++j) {
#pragma unroll
      for (int r = 0; r < 4; ++r) {
        int rr = m0 + wm * 32 + i * 16 + quad * 4 + r;
        int cc = n0 + wn * 32 + j * 16 + r16;
        osum[(long)mp * 131072 + (long)rr * 256 + cc] = acc[i][j][r];
      }
    }
  }
}

// ---- finalize: out = normalize((o0+o1)/2) @ fc_w + fc_b, f32 out ----
__global__ __launch_bounds__(64) void finalize_k(
    const float* __restrict__ o0, const float* __restrict__ o1,
    const float* __restrict__ fcw, const float* __restrict__ fcb,
    float* __restrict__ out) {
  int b = blockIdx.x, l = threadIdx.x;
  float v[4];
  float ss = 0.f;
#pragma unroll
  for (int k = 0; k < 4; ++k) {
    int j = l + 64 * k;
    v[k] = 0.5f * (o0[(long)b * 256 + j] + o1[(long)b * 256 + j]);
    ss += v[k] * v[k];
  }
#pragma unroll
  for (int off = 32; off > 0; off >>= 1) ss += __shfl_down(ss, off);
  ss = __shfl(ss, 0);
  float sc = 1.f / fmaxf(sqrtf(ss), 1e-12f);
  float p[8];
#pragma unroll
  for (int c = 0; c < 8; ++c) p[c] = 0.f;
#pragma unroll
  for (int k = 0; k < 4; ++k) {
    int j = l + 64 * k;
    float vh = v[k] * sc;
#pragma unroll
    for (int c = 0; c < 8; ++c) p[c] += vh * fcw[j * 8 + c];
  }
#pragma unroll
  for (int off = 32; off > 0; off >>= 1) {
#pragma unroll
    for (int c = 0; c < 8; ++c) p[c] += __shfl_down(p[c], off);
  }
  if (l == 0) {
#pragma unroll
    for (int c = 0; c < 8; ++c) out[b * 8 + c] = p[c] + fcb[c];
  }
}

extern "C" void kernel_launch(void* const* d_in, const int* in_sizes, int n_in,
                              void* d_out, int out_size, void* d_ws, size_t ws_size,
                              hipStream_t stream) {
  const int* ids = (const int*)d_in[0];
  const float* feats = (const float*)d_in[1];
  const int* n0i[2] = {(const int*)d_in[2], (const int*)d_in[4]};
  const int* n1i[2] = {(const int*)d_in[3], (const int*)d_in[5]};
  const int* e0i[2] = {(const int*)d_in[6], (const int*)d_in[8]};
  const int* e1i[2] = {(const int*)d_in[7], (const int*)d_in[9]};
  const float* emb[2] = {(const float*)d_in[10], (const float*)d_in[11]};
  const float* Wself = (const float*)d_in[12];
  const float* Wneigh = (const float*)d_in[13];
  const float* Wedg = (const float*)d_in[14];
  const float* Wec = (const float*)d_in[15];
  const float* bec = (const float*)d_in[16];
  const float* fcw = (const float*)d_in[17];
  const float* fcb = (const float*)d_in[18];
  float* out = (float*)d_out;

  // ---- workspace ----
  float* osum = (float*)d_ws;                               // [2][512][256] f32
  unsigned short* A1b  = (unsigned short*)(osum + 262144);  // [2][5632][576]
  unsigned short* eg0  = A1b + 6488064;                     // [2][5120][64]
  unsigned short* h01  = eg0 + 655360;                      // [2][5632][256]
  unsigned short* enew = h01 + 2883584;                     // [2][5120][64]
  unsigned short* wt1  = enew + 655360;                     // [4][256][576]
  unsigned short* wte  = wt1 + 589824;                      // [2][64][576]
  unsigned short* A3   = wte + 73728;                       // [2][512][576]

  // 1) prep: weight pack + all 14 gathers
  {
    GJobs gj; int blk = 0, nj = 0;
    auto add = [&](const float* table, const int* idx, unsigned short* o,
                   int M, int D4, int ns, int ostride, float inv) {
      gj.j[nj] = {table, idx, o, M, D4, ns, ostride, blk, inv};
      blk += (M * D4) / 256; ++nj;
    };
    for (int mp = 0; mp < 2; ++mp) {
      unsigned short* Am = A1b + (size_t)mp * 5632 * 576;
      add(feats, ids,     Am,                     512, 64, 1, 576, 1.0f);
      add(feats, n0i[mp], Am + 512 * 576,         5120, 64, 1, 576, 1.0f);
      add(feats, n0i[mp], Am + 256,               512, 64, NS, 576, 0.1f);
      add(feats, n1i[mp], Am + 512 * 576 + 256,   5120, 64, NS, 576, 0.1f);
      add(emb[mp], e0i[mp], Am + 512,             512, 16, NS, 576, 0.1f);
      add(emb[mp], e1i[mp], Am + 512 * 576 + 512, 5120, 16, NS, 576, 0.1f);
      add(emb[mp], e0i[mp], eg0 + (size_t)mp * 327680, 5120, 16, 1, 64, 1.0f);
    }
    gprep_k<<<dim3(PACKB + blk), dim3(256), 0, stream>>>(
        gj, nj, Wself, Wneigh, Wedg, Wec, wt1, wte);
  }

  // 2) layer-0 agg: h01 = relu(A1 @ WT1[mp][0]); tees h0 rows into A3
  gemm1_k<<<dim3(2, 88, 2), dim3(256), 0, stream>>>(A1b, wt1, h01, A3);

  // 3) edge update: enew = tanh([h0(rep10)|h1|eg0] @ WTe + be)
  edge_k<<<dim3(1, 80, 2), dim3(256), 0, stream>>>(h01, eg0, wte, bec, enew);

  // 4) means for layer-1 A matrix
  meanprep_k<<<dim3(80, 2), dim3(256), 0, stream>>>(h01, enew, A3);

  // 5) layer-1 agg: osum = A3 @ WT1[mp][1]
  gemm3_k<<<dim3(4, 8, 2), dim3(256), 0, stream>>>(A3, wt1, osum);

  // 6) metapath mean + L2 normalize + FC
  finalize_k<<<dim3(512), dim3(64), 0, stream>>>(osum, osum + 131072, fcw, fcb, out);
}